// Round 8
// baseline (117.926 us; speedup 1.0000x reference)
//
#include <hip/hip_runtime.h>
#include <hip/hip_fp16.h>

#define BATCH 16
#define H 512
#define W 512
#define BH 128
#define BW 128
#define HG 510   // interior rows (buffer rows 0..509 <-> pixel rows 1..510)
#define WG 510
#define PKW 512  // padded row stride of packed intermediate

// pack: (mag_bits & ~31) | o   -- o in [0,18) fits 5 bits; mag rel err ~3e-6
// o is chosen BEFORE truncation, so argmax decisions are bit-identical to ref.

// ---------------- Kernel 1: gradient + orientation, 4x4 px/thread ----------------
// At HBM floor (~11 us: 50 MB img read + 16.7 MB pk write) -- R5 evidence.
__global__ __launch_bounds__(256) void hog_grad(const float* __restrict__ img,
                                                unsigned int* __restrict__ pk)
{
    int gx = blockIdx.x * 64 + threadIdx.x;   // x-quad 0..127
    int qy = blockIdx.y * 4 + threadIdx.y;    // y-quad 0..127
    int b  = blockIdx.z;
    int x0 = gx * 4;                          // buffer col of px 0 (aligned)
    int y0 = qy * 4;                          // buffer row of output row 0
    bool edge = (x0 < 508);

    const float* im = img + (size_t)b * 3 * H * W;

    float bv[16], bx[16], by[16];
#pragma unroll
    for (int i = 0; i < 16; i++) { bv[i] = -1.f; bx[i] = 0.f; by[i] = 0.f; }

#pragma unroll
    for (int c = 0; c < 3; c++) {
        const float* base = im + (size_t)c * H * W;
        float Wr[6][6];
#pragma unroll
        for (int j = 0; j < 6; j++) {
            int pr = y0 + j; if (pr > 511) pr = 511;   // clamped rows feed only masked outputs
            const float* rowp = base + (size_t)pr * W + x0;
            float4 a = *(const float4*)rowp;
            Wr[j][0] = a.x; Wr[j][1] = a.y; Wr[j][2] = a.z; Wr[j][3] = a.w;
            if (j >= 1 && j <= 4) {
                if (edge || pr < 511) {
                    float2 f = *(const float2*)(rowp + 4);
                    Wr[j][4] = f.x; Wr[j][5] = f.y;
                } else { Wr[j][4] = 0.f; Wr[j][5] = 0.f; }
            } else {
                Wr[j][4] = edge ? rowp[4] : 0.0f;
                Wr[j][5] = 0.f;
            }
        }
#pragma unroll
        for (int r = 0; r < 4; r++) {
#pragma unroll
            for (int i = 0; i < 4; i++) {
                float dx = __fsub_rn(Wr[r + 1][i + 2], Wr[r + 1][i]);
                float dy = __fsub_rn(Wr[r + 2][i + 1], Wr[r][i + 1]);
                float v = __fadd_rn(__fmul_rn(dx, dx), __fmul_rn(dy, dy));
                int k = r * 4 + i;
                if (v > bv[k]) { bv[k] = v; bx[k] = dx; by[k] = dy; }
            }
        }
    }

    const float uu[9] = {1.0f, 0.9397f, 0.766f, 0.5f, 0.1736f, -0.1736f, -0.5f, -0.766f, -0.9397f};
    const float vv[9] = {0.0f, 0.342f, 0.6428f, 0.866f, 0.9848f, 0.9848f, 0.866f, 0.6428f, 0.342f};

#pragma unroll
    for (int r = 0; r < 4; r++) {
        int y = y0 + r;
        if (y >= HG) break;
        unsigned int pkv[4];
#pragma unroll
        for (int i = 0; i < 4; i++) {
            int k = r * 4 + i;
            float mg = __fsqrt_rn(bv[k]);
            float d[9];
#pragma unroll
            for (int o = 0; o < 9; o++)
                d[o] = __fadd_rn(__fmul_rn(uu[o], bx[k]), __fmul_rn(vv[o], by[k]));
            float best = -1e30f; int bo = 0;
#pragma unroll
            for (int o = 0; o < 9; o++) { if (d[o] > best) { best = d[o]; bo = o; } }
#pragma unroll
            for (int o = 0; o < 9; o++) { float nd = -d[o]; if (nd > best) { best = nd; bo = o + 9; } }
            unsigned int v = (__float_as_uint(mg) & 0xFFFFFFE0u) | (unsigned int)bo;
            pkv[i] = (x0 + i < WG) ? v : 0u;
        }
        uint4 o4 = make_uint4(pkv[0], pkv[1], pkv[2], pkv[3]);
        *(uint4*)(pk + ((size_t)b * HG + y) * PKW + x0) = o4;
    }
}

// ---------------- Kernel 2: per-cell 8x8 bilinear gather -> hist(fp16x2) + norm ----------------
// R8: t-major padded LDS layout hl[t*10 + o9] -- each thread's 9 half2 bins
// contiguous (pad to 10 dwords => 40B base, 8B-aligned => b64 init/readout).
// DS ops 200 -> 148/thread. gcd(10,32)=2 => 2-way base aliasing (free, m136).
// Hoisted unconditional loads (R7), 2 alternating buffers (R4), fp16 packing
// (R6), NO LDS fp32 atomics (~5x slower, R3).
__global__ __launch_bounds__(256) void hog_hist(const unsigned int* __restrict__ pk,
                                                __half2* __restrict__ hist,
                                                float* __restrict__ nrm)
{
    __shared__ __half2 hl0[256 * 10];
    __shared__ __half2 hl1[256 * 10];
    int cx = threadIdx.x;                   // 0..127
    int cy = blockIdx.y * 2 + threadIdx.y;  // 0..127
    int b = blockIdx.z;
    int t = threadIdx.y * 128 + cx;
    __half2* h0 = hl0 + t * 10;
    __half2* h1 = hl1 + t * 10;

    const float wt[8] = {0.125f, 0.375f, 0.625f, 0.875f, 0.875f, 0.625f, 0.375f, 0.125f};
    const float wl[4] = {0.0f, 0.125f, 0.375f, 0.625f};   // pixels 4c-4..4c-1
    const float wm[4] = {0.875f, 0.875f, 0.625f, 0.375f}; // pixels 4c..4c+3

    const unsigned int* pb = pk + (size_t)b * HG * PKW;
    int ry0 = 4 * cy - 3;
    int xb = 4 * cx;
    int xL = (cx > 0) ? xb - 4 : xb;        // clamped; weight-zeroed below
    int xR = (cx < 127) ? xb + 4 : xb;      // clamped; weight-zeroed below
    float wLm = (cx > 0) ? 1.0f : 0.0f;
    float wRm = (cx < 127) ? 1.0f : 0.0f;
    // M.z/M.w at cx==127 read pk cols 510/511 (zero-padded by k1) -> safe.

    // ---- hoisted loads: issue everything, wait once ----
    uint4 Lv[8], Mv[8]; unsigned Xv[8]; float wyv[8];
#pragma unroll
    for (int ky = 0; ky < 8; ky++) {
        int ry = ry0 + ky;
        bool ok = (unsigned)ry < (unsigned)HG;
        int ryc = ok ? ry : (ry < 0 ? 0 : HG - 1);
        const unsigned int* row = pb + (size_t)ryc * PKW;
        Lv[ky] = *(const uint4*)(row + xL);
        Mv[ky] = *(const uint4*)(row + xb);
        Xv[ky] = row[xR];
        wyv[ky] = ok ? wt[ky] : 0.0f;
    }

    // vectorized zero-init: 4x b64 + 1x b32 per buffer (base 40B => 8B-aligned)
    {
        float2 z = make_float2(0.f, 0.f);
        *(float2*)(h0 + 0) = z; *(float2*)(h0 + 2) = z;
        *(float2*)(h0 + 4) = z; *(float2*)(h0 + 6) = z;
        h0[8] = __halves2half2(__ushort_as_half(0), __ushort_as_half(0));
        *(float2*)(h1 + 0) = z; *(float2*)(h1 + 2) = z;
        *(float2*)(h1 + 4) = z; *(float2*)(h1 + 6) = z;
        h1[8] = __halves2half2(__ushort_as_half(0), __ushort_as_half(0));
    }

#define ACC(B, P, WW) { unsigned _p = (P); unsigned _o = _p & 31u;                         \
        __half _hv = __float2half((WW) * __uint_as_float(_p & 0xFFFFFFE0u));               \
        bool _lo = _o < 9u; unsigned _o9 = _lo ? _o : _o - 9u;                             \
        __half2 _ad = _lo ? __halves2half2(_hv, __ushort_as_half(0))                       \
                          : __halves2half2(__ushort_as_half(0), _hv);                      \
        B[_o9] = __hadd2(B[_o9], _ad); }

#pragma unroll
    for (int ky = 0; ky < 8; ky++) {
        float wy = wyv[ky];
        uint4 L = Lv[ky], M = Mv[ky];
        ACC(h0, L.y, (wy * wl[1]) * wLm);
        ACC(h1, L.z, (wy * wl[2]) * wLm);
        ACC(h0, L.w, (wy * wl[3]) * wLm);
        ACC(h1, M.x, wy * wm[0]);
        ACC(h0, M.y, wy * wm[1]);
        ACC(h1, M.z, wy * wm[2]);
        ACC(h0, M.w, wy * wm[3]);
        ACC(h1, Xv[ky], (wy * 0.125f) * wRm);
    }
#undef ACC

    // vectorized readout: 4x b64 + 1x b32 per buffer
    unsigned a0[9], a1[9];
    {
        uint2 p;
        p = *(uint2*)(h0 + 0); a0[0] = p.x; a0[1] = p.y;
        p = *(uint2*)(h0 + 2); a0[2] = p.x; a0[3] = p.y;
        p = *(uint2*)(h0 + 4); a0[4] = p.x; a0[5] = p.y;
        p = *(uint2*)(h0 + 6); a0[6] = p.x; a0[7] = p.y;
        a0[8] = *(unsigned*)(h0 + 8);
        p = *(uint2*)(h1 + 0); a1[0] = p.x; a1[1] = p.y;
        p = *(uint2*)(h1 + 2); a1[2] = p.x; a1[3] = p.y;
        p = *(uint2*)(h1 + 4); a1[4] = p.x; a1[5] = p.y;
        p = *(uint2*)(h1 + 6); a1[6] = p.x; a1[7] = p.y;
        a1[8] = *(unsigned*)(h1 + 8);
    }

    float s = 0.0f;
#pragma unroll
    for (int o = 0; o < 9; o++) {
        __half2 hh = __hadd2(*(__half2*)&a0[o], *(__half2*)&a1[o]);
        hist[(((size_t)b * 9 + o) * BH + cy) * BW + cx] = hh;
        float2 f = __half22float2(hh);
        float ss = f.x + f.y;
        s += ss * ss;
    }
    nrm[((size_t)b * BH + cy) * BW + cx] = s;
}

// ---------------- Kernel 3: normalization + features, 4 cells/thread ----------------
__global__ __launch_bounds__(256) void hog_feat(const __half2* __restrict__ hist,
                                                const float* __restrict__ nrm,
                                                float* __restrict__ out)
{
    int tx = threadIdx.x;                   // 0..31 (x-quad)
    int oy = blockIdx.y * 8 + threadIdx.y;  // 0..127
    int b  = blockIdx.z;
    int cx0 = tx * 4;

    if (oy == 0 || oy == BH - 1) {
        float4 z4 = make_float4(0.f, 0.f, 0.f, 0.f);
#pragma unroll
        for (int c = 0; c < 31; c++)
            *(float4*)(out + (((size_t)b * 31 + c) * BH + oy) * BW + cx0) = z4;
        return;
    }

    float v1[4], v2[4], v3[4], v4[4];
    {
        const float* nb = nrm + (size_t)b * BH * BW;
        float nn[3][6];
#pragma unroll
        for (int r = 0; r < 3; r++) {
            const float* rp = nb + (size_t)(oy - 1 + r) * BW + cx0;
#pragma unroll
            for (int j = 0; j < 6; j++) nn[r][j] = rp[j - 1];
        }
#pragma unroll
        for (int i = 0; i < 4; i++) {
            float T11 = nn[1][i+1] + nn[2][i+1] + nn[1][i+2] + nn[2][i+2];
            float T01 = nn[0][i+1] + nn[1][i+1] + nn[0][i+2] + nn[1][i+2];
            float T10 = nn[1][i]   + nn[2][i]   + nn[1][i+1] + nn[2][i+1];
            float T00 = nn[0][i]   + nn[1][i]   + nn[0][i+1] + nn[1][i+1];
            v1[i] = 1.0f / __fsqrt_rn(T11 + 1e-4f);
            v2[i] = 1.0f / __fsqrt_rn(T01 + 1e-4f);
            v3[i] = 1.0f / __fsqrt_rn(T10 + 1e-4f);
            v4[i] = 1.0f / __fsqrt_rn(T00 + 1e-4f);
        }
    }

    float h[4][18];
#pragma unroll
    for (int o = 0; o < 9; o++) {
        uint4 q = *(const uint4*)(hist + (((size_t)b * 9 + o) * BH + oy) * BW + cx0);
        unsigned vs[4] = {q.x, q.y, q.z, q.w};
#pragma unroll
        for (int i = 0; i < 4; i++) {
            float2 f = __half22float2(*(__half2*)&vs[i]);
            h[i][o] = f.x; h[i][o + 9] = f.y;
        }
    }

    bool msk[4];
#pragma unroll
    for (int i = 0; i < 4; i++) { int cxi = cx0 + i; msk[i] = (cxi >= 1 && cxi <= 126); }

    float t1[4] = {0,0,0,0}, t2[4] = {0,0,0,0}, t3[4] = {0,0,0,0}, t4[4] = {0,0,0,0};
    float* ob = out + ((size_t)b * 31) * BH * BW + (size_t)oy * BW + cx0;

#pragma unroll
    for (int o = 0; o < 18; o++) {
        float st[4];
#pragma unroll
        for (int i = 0; i < 4; i++) {
            float s = h[i][o];
            float a1 = fminf(s * v1[i], 0.2f);
            float a2 = fminf(s * v2[i], 0.2f);
            float a3 = fminf(s * v3[i], 0.2f);
            float a4 = fminf(s * v4[i], 0.2f);
            t1[i] += a1; t2[i] += a2; t3[i] += a3; t4[i] += a4;
            st[i] = msk[i] ? 0.5f * (a1 + a2 + a3 + a4) : 0.f;
        }
        *(float4*)(ob + (size_t)o * BH * BW) = make_float4(st[0], st[1], st[2], st[3]);
    }
#pragma unroll
    for (int o = 0; o < 9; o++) {
        float st[4];
#pragma unroll
        for (int i = 0; i < 4; i++) {
            float ss = h[i][o] + h[i][o + 9];
            float a1 = fminf(ss * v1[i], 0.2f);
            float a2 = fminf(ss * v2[i], 0.2f);
            float a3 = fminf(ss * v3[i], 0.2f);
            float a4 = fminf(ss * v4[i], 0.2f);
            st[i] = msk[i] ? 0.5f * (a1 + a2 + a3 + a4) : 0.f;
        }
        *(float4*)(ob + (size_t)(18 + o) * BH * BW) = make_float4(st[0], st[1], st[2], st[3]);
    }
    {
        float s1[4], s2[4], s3[4], s4[4];
#pragma unroll
        for (int i = 0; i < 4; i++) {
            s1[i] = msk[i] ? 0.2357f * t1[i] : 0.f;
            s2[i] = msk[i] ? 0.2357f * t2[i] : 0.f;
            s3[i] = msk[i] ? 0.2357f * t3[i] : 0.f;
            s4[i] = msk[i] ? 0.2357f * t4[i] : 0.f;
        }
        *(float4*)(ob + (size_t)27 * BH * BW) = make_float4(s1[0], s1[1], s1[2], s1[3]);
        *(float4*)(ob + (size_t)28 * BH * BW) = make_float4(s2[0], s2[1], s2[2], s2[3]);
        *(float4*)(ob + (size_t)29 * BH * BW) = make_float4(s3[0], s3[1], s3[2], s3[3]);
        *(float4*)(ob + (size_t)30 * BH * BW) = make_float4(s4[0], s4[1], s4[2], s4[3]);
    }
}

extern "C" void kernel_launch(void* const* d_in, const int* in_sizes, int n_in,
                              void* d_out, int out_size, void* d_ws, size_t ws_size,
                              hipStream_t stream)
{
    const float* img = (const float*)d_in[0];
    float* out = (float*)d_out;
    char* ws = (char*)d_ws;

    // workspace layout (256-aligned offsets):
    //   pk   : 16*510*512*4 = 16,711,680  @ 0
    //   hist : 16*9*128*128*4 = 9,437,184 @ 16,715,776  (half2-packed bins o|o+9)
    //   nrm  : 16*128*128*4 = 1,048,576  @ 26,152,960   (end 27,201,536)
    unsigned int* pk = (unsigned int*)ws;
    __half2* hist    = (__half2*)(ws + 16715776);
    float* nrm       = (float*)(ws + 26152960);

    dim3 b1(64, 4, 1), g1(2, 32, BATCH);
    hog_grad<<<g1, b1, 0, stream>>>(img, pk);

    dim3 b2(128, 2, 1), g2(1, BH / 2, BATCH);
    hog_hist<<<g2, b2, 0, stream>>>(pk, hist, nrm);

    dim3 b3(32, 8, 1), g3(1, BH / 8, BATCH);
    hog_feat<<<g3, b3, 0, stream>>>(hist, nrm, out);
}

// Round 9
// 116.380 us; speedup vs baseline: 1.0133x; 1.0133x over previous
//
#include <hip/hip_runtime.h>
#include <hip/hip_fp16.h>

#define BATCH 16
#define H 512
#define W 512
#define BH 128
#define BW 128
#define HG 510   // interior rows (buffer rows 0..509 <-> pixel rows 1..510)
#define WG 510
#define PKW 512  // padded row stride of packed intermediate

// pack: (mag_bits & ~31) | o   -- o in [0,18) fits 5 bits; mag rel err ~3e-6
// o is chosen BEFORE truncation, so argmax decisions are bit-identical to ref.

// ---------------- Kernel 1: gradient + orientation, 4x2 px/thread ----------------
// R9: fix the 49.6us latency disaster found in R8's profile:
//  - __launch_bounds__(256,2): VGPR cap 256 (was implicitly ~68 -> spill/serialize)
//  - 4x2 tile: ~90 live VGPRs -> ~4 waves/SIMD without spills
//  - ALL 8 loads per channel unconditional & batched (one address-clamp cndmask
//    for the single OOB corner row511/x0=508; garbage feeds only masked px)
//  - 2048 blocks = 32 waves/CU
__global__ __launch_bounds__(256, 2) void hog_grad(const float* __restrict__ img,
                                                   unsigned int* __restrict__ pk)
{
    int gx = blockIdx.x * 64 + threadIdx.x;   // x-quad 0..127
    int pp = blockIdx.y * 4 + threadIdx.y;    // row-pair 0..255
    int b  = blockIdx.z;
    if (pp >= 255) return;                    // pairs 0..254 cover buffer rows 0..509
    int x0 = gx * 4;                          // buffer col of px 0 (16B-aligned)
    int y0 = pp * 2;                          // buffer rows y0, y0+1 (pixel rows y0+1, y0+2)
    bool edge = (x0 < 508);

    const float* im = img + (size_t)b * 3 * H * W;

    float bv[8], bx[8], by[8];
#pragma unroll
    for (int i = 0; i < 8; i++) { bv[i] = -1.f; bx[i] = 0.f; by[i] = 0.f; }

#pragma unroll
    for (int c = 0; c < 3; c++) {
        const float* base = im + (size_t)c * H * W;
        // window: pixel rows y0..y0+3, cols x0..x0+5 -- 8 unconditional loads
        float Wr[4][6];
#pragma unroll
        for (int j = 0; j < 4; j++) {
            int pr = y0 + j;                  // <= 511
            const float* rowp = base + (size_t)pr * W + x0;
            float4 a = *(const float4*)rowp;
            // f2 at cols x0+4..x0+5: in-bounds except pr==511 && x0==508 (&& c==2, b==15).
            // Clamp offset 4->2 there; garbage feeds only store-masked px 510/511.
            int off = (edge || pr < 511) ? 4 : 2;
            float2 f = *(const float2*)(rowp + off);
            Wr[j][0] = a.x; Wr[j][1] = a.y; Wr[j][2] = a.z; Wr[j][3] = a.w;
            Wr[j][4] = f.x; Wr[j][5] = f.y;
        }
#pragma unroll
        for (int r = 0; r < 2; r++) {         // output buffer row y0+r
#pragma unroll
            for (int i = 0; i < 4; i++) {
                float dx = __fsub_rn(Wr[r + 1][i + 2], Wr[r + 1][i]);
                float dy = __fsub_rn(Wr[r + 2][i + 1], Wr[r][i + 1]);
                float v = __fadd_rn(__fmul_rn(dx, dx), __fmul_rn(dy, dy));
                int k = r * 4 + i;
                if (v > bv[k]) { bv[k] = v; bx[k] = dx; by[k] = dy; }
            }
        }
    }

    const float uu[9] = {1.0f, 0.9397f, 0.766f, 0.5f, 0.1736f, -0.1736f, -0.5f, -0.766f, -0.9397f};
    const float vv[9] = {0.0f, 0.342f, 0.6428f, 0.866f, 0.9848f, 0.9848f, 0.866f, 0.6428f, 0.342f};

#pragma unroll
    for (int r = 0; r < 2; r++) {
        int y = y0 + r;                       // <= 509, always valid
        unsigned int pkv[4];
#pragma unroll
        for (int i = 0; i < 4; i++) {
            int k = r * 4 + i;
            float mg = __fsqrt_rn(bv[k]);
            float d[9];
#pragma unroll
            for (int o = 0; o < 9; o++)
                d[o] = __fadd_rn(__fmul_rn(uu[o], bx[k]), __fmul_rn(vv[o], by[k]));
            float best = -1e30f; int bo = 0;
#pragma unroll
            for (int o = 0; o < 9; o++) { if (d[o] > best) { best = d[o]; bo = o; } }
#pragma unroll
            for (int o = 0; o < 9; o++) { float nd = -d[o]; if (nd > best) { best = nd; bo = o + 9; } }
            unsigned int v = (__float_as_uint(mg) & 0xFFFFFFE0u) | (unsigned int)bo;
            pkv[i] = (x0 + i < WG) ? v : 0u;  // zero pad cols 510/511
        }
        uint4 o4 = make_uint4(pkv[0], pkv[1], pkv[2], pkv[3]);
        *(uint4*)(pk + ((size_t)b * HG + y) * PKW + x0) = o4;
    }
}

// ---------------- Kernel 2: per-cell 8x8 bilinear gather -> hist(fp16x2) + norm ----------------
// R7 version (o-major LDS; R8's t-major was neutral). Hoisted unconditional
// loads (R7), 2 alternating buffers (R4), fp16 packing (R6), NO LDS fp32
// atomics (~5x slower, R3).
__global__ __launch_bounds__(256) void hog_hist(const unsigned int* __restrict__ pk,
                                                __half2* __restrict__ hist,
                                                float* __restrict__ nrm)
{
    __shared__ __half2 hl0[9 * 256];
    __shared__ __half2 hl1[9 * 256];
    int cx = threadIdx.x;                   // 0..127
    int cy = blockIdx.y * 2 + threadIdx.y;  // 0..127
    int b = blockIdx.z;
    int t = threadIdx.y * 128 + cx;

    const float wt[8] = {0.125f, 0.375f, 0.625f, 0.875f, 0.875f, 0.625f, 0.375f, 0.125f};
    const float wl[4] = {0.0f, 0.125f, 0.375f, 0.625f};   // pixels 4c-4..4c-1
    const float wm[4] = {0.875f, 0.875f, 0.625f, 0.375f}; // pixels 4c..4c+3

    const unsigned int* pb = pk + (size_t)b * HG * PKW;
    int ry0 = 4 * cy - 3;
    int xb = 4 * cx;
    int xL = (cx > 0) ? xb - 4 : xb;        // clamped; weight-zeroed below
    int xR = (cx < 127) ? xb + 4 : xb;      // clamped; weight-zeroed below
    float wLm = (cx > 0) ? 1.0f : 0.0f;
    float wRm = (cx < 127) ? 1.0f : 0.0f;
    // M.z/M.w at cx==127 read pk cols 510/511 (zero-padded by k1) -> safe.

    // ---- hoisted loads: issue everything, wait once ----
    uint4 Lv[8], Mv[8]; unsigned Xv[8]; float wyv[8];
#pragma unroll
    for (int ky = 0; ky < 8; ky++) {
        int ry = ry0 + ky;
        bool ok = (unsigned)ry < (unsigned)HG;
        int ryc = ok ? ry : (ry < 0 ? 0 : HG - 1);
        const unsigned int* row = pb + (size_t)ryc * PKW;
        Lv[ky] = *(const uint4*)(row + xL);
        Mv[ky] = *(const uint4*)(row + xb);
        Xv[ky] = row[xR];
        wyv[ky] = ok ? wt[ky] : 0.0f;
    }

    const __half2 z2 = __halves2half2(__ushort_as_half(0), __ushort_as_half(0));
#pragma unroll
    for (int o = 0; o < 9; o++) { hl0[o * 256 + t] = z2; hl1[o * 256 + t] = z2; }
    // per-thread private columns: no barrier; bank = t%32 -> 2-way (free)

#define ACC(B, P, WW) { unsigned _p = (P); unsigned _o = _p & 31u;                         \
        __half _hv = __float2half((WW) * __uint_as_float(_p & 0xFFFFFFE0u));               \
        bool _lo = _o < 9u; unsigned _o9 = _lo ? _o : _o - 9u;                             \
        __half2 _ad = _lo ? __halves2half2(_hv, __ushort_as_half(0))                       \
                          : __halves2half2(__ushort_as_half(0), _hv);                      \
        B[_o9 * 256 + t] = __hadd2(B[_o9 * 256 + t], _ad); }

#pragma unroll
    for (int ky = 0; ky < 8; ky++) {
        float wy = wyv[ky];
        uint4 L = Lv[ky], M = Mv[ky];
        ACC(hl0, L.y, (wy * wl[1]) * wLm);
        ACC(hl1, L.z, (wy * wl[2]) * wLm);
        ACC(hl0, L.w, (wy * wl[3]) * wLm);
        ACC(hl1, M.x, wy * wm[0]);
        ACC(hl0, M.y, wy * wm[1]);
        ACC(hl1, M.z, wy * wm[2]);
        ACC(hl0, M.w, wy * wm[3]);
        ACC(hl1, Xv[ky], (wy * 0.125f) * wRm);
    }
#undef ACC

    float s = 0.0f;
#pragma unroll
    for (int o = 0; o < 9; o++) {
        __half2 hh = __hadd2(hl0[o * 256 + t], hl1[o * 256 + t]);
        hist[(((size_t)b * 9 + o) * BH + cy) * BW + cx] = hh;
        float2 f = __half22float2(hh);
        float ss = f.x + f.y;
        s += ss * ss;
    }
    nrm[((size_t)b * BH + cy) * BW + cx] = s;
}

// ---------------- Kernel 3: normalization + features, 4 cells/thread ----------------
__global__ __launch_bounds__(256) void hog_feat(const __half2* __restrict__ hist,
                                                const float* __restrict__ nrm,
                                                float* __restrict__ out)
{
    int tx = threadIdx.x;                   // 0..31 (x-quad)
    int oy = blockIdx.y * 8 + threadIdx.y;  // 0..127
    int b  = blockIdx.z;
    int cx0 = tx * 4;

    if (oy == 0 || oy == BH - 1) {
        float4 z4 = make_float4(0.f, 0.f, 0.f, 0.f);
#pragma unroll
        for (int c = 0; c < 31; c++)
            *(float4*)(out + (((size_t)b * 31 + c) * BH + oy) * BW + cx0) = z4;
        return;
    }

    float v1[4], v2[4], v3[4], v4[4];
    {
        const float* nb = nrm + (size_t)b * BH * BW;
        float nn[3][6];
#pragma unroll
        for (int r = 0; r < 3; r++) {
            const float* rp = nb + (size_t)(oy - 1 + r) * BW + cx0;
#pragma unroll
            for (int j = 0; j < 6; j++) nn[r][j] = rp[j - 1];
        }
#pragma unroll
        for (int i = 0; i < 4; i++) {
            float T11 = nn[1][i+1] + nn[2][i+1] + nn[1][i+2] + nn[2][i+2];
            float T01 = nn[0][i+1] + nn[1][i+1] + nn[0][i+2] + nn[1][i+2];
            float T10 = nn[1][i]   + nn[2][i]   + nn[1][i+1] + nn[2][i+1];
            float T00 = nn[0][i]   + nn[1][i]   + nn[0][i+1] + nn[1][i+1];
            v1[i] = 1.0f / __fsqrt_rn(T11 + 1e-4f);
            v2[i] = 1.0f / __fsqrt_rn(T01 + 1e-4f);
            v3[i] = 1.0f / __fsqrt_rn(T10 + 1e-4f);
            v4[i] = 1.0f / __fsqrt_rn(T00 + 1e-4f);
        }
    }

    float h[4][18];
#pragma unroll
    for (int o = 0; o < 9; o++) {
        uint4 q = *(const uint4*)(hist + (((size_t)b * 9 + o) * BH + oy) * BW + cx0);
        unsigned vs[4] = {q.x, q.y, q.z, q.w};
#pragma unroll
        for (int i = 0; i < 4; i++) {
            float2 f = __half22float2(*(__half2*)&vs[i]);
            h[i][o] = f.x; h[i][o + 9] = f.y;
        }
    }

    bool msk[4];
#pragma unroll
    for (int i = 0; i < 4; i++) { int cxi = cx0 + i; msk[i] = (cxi >= 1 && cxi <= 126); }

    float t1[4] = {0,0,0,0}, t2[4] = {0,0,0,0}, t3[4] = {0,0,0,0}, t4[4] = {0,0,0,0};
    float* ob = out + ((size_t)b * 31) * BH * BW + (size_t)oy * BW + cx0;

#pragma unroll
    for (int o = 0; o < 18; o++) {
        float st[4];
#pragma unroll
        for (int i = 0; i < 4; i++) {
            float s = h[i][o];
            float a1 = fminf(s * v1[i], 0.2f);
            float a2 = fminf(s * v2[i], 0.2f);
            float a3 = fminf(s * v3[i], 0.2f);
            float a4 = fminf(s * v4[i], 0.2f);
            t1[i] += a1; t2[i] += a2; t3[i] += a3; t4[i] += a4;
            st[i] = msk[i] ? 0.5f * (a1 + a2 + a3 + a4) : 0.f;
        }
        *(float4*)(ob + (size_t)o * BH * BW) = make_float4(st[0], st[1], st[2], st[3]);
    }
#pragma unroll
    for (int o = 0; o < 9; o++) {
        float st[4];
#pragma unroll
        for (int i = 0; i < 4; i++) {
            float ss = h[i][o] + h[i][o + 9];
            float a1 = fminf(ss * v1[i], 0.2f);
            float a2 = fminf(ss * v2[i], 0.2f);
            float a3 = fminf(ss * v3[i], 0.2f);
            float a4 = fminf(ss * v4[i], 0.2f);
            st[i] = msk[i] ? 0.5f * (a1 + a2 + a3 + a4) : 0.f;
        }
        *(float4*)(ob + (size_t)(18 + o) * BH * BW) = make_float4(st[0], st[1], st[2], st[3]);
    }
    {
        float s1[4], s2[4], s3[4], s4[4];
#pragma unroll
        for (int i = 0; i < 4; i++) {
            s1[i] = msk[i] ? 0.2357f * t1[i] : 0.f;
            s2[i] = msk[i] ? 0.2357f * t2[i] : 0.f;
            s3[i] = msk[i] ? 0.2357f * t3[i] : 0.f;
            s4[i] = msk[i] ? 0.2357f * t4[i] : 0.f;
        }
        *(float4*)(ob + (size_t)27 * BH * BW) = make_float4(s1[0], s1[1], s1[2], s1[3]);
        *(float4*)(ob + (size_t)28 * BH * BW) = make_float4(s2[0], s2[1], s2[2], s2[3]);
        *(float4*)(ob + (size_t)29 * BH * BW) = make_float4(s3[0], s3[1], s3[2], s3[3]);
        *(float4*)(ob + (size_t)30 * BH * BW) = make_float4(s4[0], s4[1], s4[2], s4[3]);
    }
}

extern "C" void kernel_launch(void* const* d_in, const int* in_sizes, int n_in,
                              void* d_out, int out_size, void* d_ws, size_t ws_size,
                              hipStream_t stream)
{
    const float* img = (const float*)d_in[0];
    float* out = (float*)d_out;
    char* ws = (char*)d_ws;

    // workspace layout (256-aligned offsets):
    //   pk   : 16*510*512*4 = 16,711,680  @ 0
    //   hist : 16*9*128*128*4 = 9,437,184 @ 16,715,776  (half2-packed bins o|o+9)
    //   nrm  : 16*128*128*4 = 1,048,576  @ 26,152,960   (end 27,201,536)
    unsigned int* pk = (unsigned int*)ws;
    __half2* hist    = (__half2*)(ws + 16715776);
    float* nrm       = (float*)(ws + 26152960);

    dim3 b1(64, 4, 1), g1(2, 64, BATCH);
    hog_grad<<<g1, b1, 0, stream>>>(img, pk);

    dim3 b2(128, 2, 1), g2(1, BH / 2, BATCH);
    hog_hist<<<g2, b2, 0, stream>>>(pk, hist, nrm);

    dim3 b3(32, 8, 1), g3(1, BH / 8, BATCH);
    hog_feat<<<g3, b3, 0, stream>>>(hist, nrm, out);
}